// Round 5
// baseline (122.884 us; speedup 1.0000x reference)
//
#include <hip/hip_runtime.h>
#include <math.h>

#define N_G 512
#define IMG_H 324
#define IMG_W 332
#define N_C 120
#define HW (IMG_H*IMG_W)
#define TSX 21                 // tiles in x (16 px)
#define TSY 81                 // tiles in y (4 px)
#define NT (TSX*TSY)
#define NBLK (NT*4)            // 4 channel-split blocks per tile

// 4 blocks per 16x4 tile; block cq owns interleaved float4 channel groups
//   g = cq + 4k (k=0..7, g<30): disjoint outputs, no cross-block combine.
// BARRIER-FREE main loop: every wave's lanes are the same 64 pixels, so each
// wave redundantly computes the per-pixel alpha/transmittance chain in
// registers (~identical cost to reading a staged copy back from LDS) and
// accumulates its own 2 float4 channel groups from broadcast global loads of
// spec (245 KB, L2-resident). No buf/sbuf staging, no wave0-serial scan, no
// main-loop __syncthreads: waves slip freely, latency-hidden at 24 waves/CU.
//   prep : project 2 gaussians/thread into registers (bbox, cov, op, depth)
//   build: ballot-compact hits -> depth keys -> rank-scan (== ref argsort)
//          -> prm[rank] in LDS  (3 barriers, then none)
//   main : per wave, j = 0..nh-1 in depth order:
//            2x uniform ds_read_b128 (prm) -> e; ballot(e>-30) dead-skip;
//            a=exp2(e); wv=a*T; T*=(1-a); 2x broadcast dwordx4 (spec); 8 fma
//            all-lanes T<1e-5 -> break (front-to-back: remainder <= T)
//   epilogue: store 2 groups/wave; cq2/w0 depth, cq3/w0 A_final.

__global__ __launch_bounds__(256, 6) void k_render(
    const float* __restrict__ pos, const float* __restrict__ scales,
    const float* __restrict__ opac, const float* __restrict__ Km,
    const float* __restrict__ Em, const float* __restrict__ spec,
    const float* __restrict__ tm, float* __restrict__ out)
{
  __shared__ float prm[N_G*8];          // rank-sorted hit params (16 KB)
  __shared__ float key[N_G+4];          // depth keys for rank-scan (2 KB)
  __shared__ int wcnt[4];
  // total ~18.5 KB -> 6 blocks/CU (24 waves/CU)

  const int tid  = threadIdx.x;
  const int w    = tid >> 6;
  const int lane = tid & 63;
  const int tx = lane & 15, ty = lane >> 4;
  const unsigned long long ltm = (1ull << lane) - 1ull;

  const int t  = blockIdx.x >> 2;       // tile
  const int cq = blockIdx.x & 3;        // channel quarter

  // ---- prep: project 2 gaussians per thread into registers ----
  float psx[2], psy[2], pc00[2], pc11[2], pl2[2], pd[2];
  float bxmin[2], bxmax[2], bymin[2], bymax[2];
  {
    const float E0=Em[0],E1=Em[1],E2=Em[2],E3=Em[3],
                E4=Em[4],E5=Em[5],E6=Em[6],E7=Em[7],
                E8=Em[8],E9=Em[9],E10=Em[10],E11=Em[11];
    const float K0=Km[0],K1=Km[1],K2=Km[2],
                K3=Km[3],K4=Km[4],K5=Km[5],
                K6=Km[6],K7=Km[7],K8=Km[8];
    #pragma unroll
    for (int q = 0; q < 2; ++q) {
      const int g = w*128 + lane + q*64;           // original index (wave-major)
      float p0 = pos[g*3+0], p1 = pos[g*3+1], p2 = pos[g*3+2];
      float cam0 = E0*p0 + E1*p1 + E2*p2  + E3;
      float cam1 = E4*p0 + E5*p1 + E6*p2  + E7;
      float cam2 = E8*p0 + E9*p1 + E10*p2 + E11;
      float pr0 = K0*cam0 + K1*cam1 + K2*cam2;
      float pr1 = K3*cam0 + K4*cam1 + K5*cam2;
      float pr2 = K6*cam0 + K7*cam1 + K8*cam2;
      float inv = 1.0f/(pr2 + 1e-6f);
      float sx = pr0*inv, sy = pr1*inv;
      float depth = cam2;
      bool valid = (depth > 0.01f) && (depth < 100.0f)
                && (sx > -100.0f) && (sx < (float)IMG_W + 100.0f)
                && (sy > -100.0f) && (sy < (float)IMG_H + 100.0f);
      bool off = (sx < -(float)IMG_W) || (sx > 2.0f*(float)IMG_W)
              || (sy < -(float)IMG_H) || (sy > 2.0f*(float)IMG_H);
      bool skip = off || (!valid);
      float s0 = scales[g*3+0], s1 = scales[g*3+1];
      float v0 = s0*s0 + 1e-4f, v1 = s1*s1 + 1e-4f;
      const float HL2E = 0.72134752f;              // 0.5*log2(e)
      psx[q] = sx; psy[q] = sy;
      pc00[q] = HL2E/v0; pc11[q] = HL2E/v1;
      pl2[q] = __log2f(skip ? 0.0f : opac[g]);     // op=0 -> -inf -> exp2 -> 0
      pd[q]  = depth;
      float rx = 6.0f*sqrtf(v0);                   // mahal cutoff 36 (6 sigma)
      float ry = 6.0f*sqrtf(v1);
      bxmin[q] = skip ?  1e9f : sx - rx;
      bxmax[q] = skip ? -1e9f : sx + rx;
      bymin[q] = skip ?  1e9f : sy - ry;
      bymax[q] = skip ? -1e9f : sy + ry;
    }
  }

  // center-out bijection: heavy central tiles get the lowest blockIdx
  const int jx = t % TSX, ky = t / TSX;
  const int bx = 10 + ((jx & 1) ? ((jx+1)>>1) : -((jx+1)>>1));
  const int by = 40 + ((ky & 1) ? ((ky+1)>>1) : -((ky+1)>>1));

  const int x = bx*16 + tx;
  const int y = by*4 + ty;
  const bool inb = (x < IMG_W) && (y < IMG_H);
  const float px = (float)min(x, IMG_W-1);
  const float py = (float)min(y, IMG_H-1);
  const float wxmin = (float)(bx*16), wxmax = wxmin + 15.0f;
  const float wymin = (float)(by*4),  wymax = wymin + 3.0f;

  // ---- build: ballot compaction + per-tile depth rank-sort ----
  bool h0 = !(bxmin[0] > wxmax || bxmax[0] < wxmin ||
              bymin[0] > wymax || bymax[0] < wymin);
  bool h1 = !(bxmin[1] > wxmax || bxmax[1] < wxmin ||
              bymin[1] > wymax || bymax[1] < wymin);
  unsigned long long m0 = __ballot(h0), m1 = __ballot(h1);
  int c0 = __popcll(m0);
  if (lane == 0) wcnt[w] = c0 + __popcll(m1);
  __syncthreads();
  int offw = 0;
  #pragma unroll
  for (int k = 0; k < 4; ++k) if (k < w) offw += wcnt[k];
  const int nh = wcnt[0] + wcnt[1] + wcnt[2] + wcnt[3];
  // compacted depth keys (compaction order == original-index order)
  const int p0 = offw + __popcll(m0 & ltm);
  const int p1 = offw + c0 + __popcll(m1 & ltm);
  if (h0) key[p0] = pd[0];
  if (h1) key[p1] = pd[1];
  if (tid < 4) key[nh + tid] = 1e30f;            // pad for float4 scan
  __syncthreads();

  // rank-scan (broadcast b128 reads); stable tie-break by compacted position
  if (h0 | h1) {
    int r0 = 0, r1 = 0;
    const float d0 = pd[0], d1 = pd[1];
    for (int j = 0; j < nh; j += 4) {
      float4 k4 = *(const float4*)&key[j];
      if (h0) {
        r0 += (k4.x < d0 || (k4.x == d0 && j+0 < p0)) ? 1 : 0;
        r0 += (k4.y < d0 || (k4.y == d0 && j+1 < p0)) ? 1 : 0;
        r0 += (k4.z < d0 || (k4.z == d0 && j+2 < p0)) ? 1 : 0;
        r0 += (k4.w < d0 || (k4.w == d0 && j+3 < p0)) ? 1 : 0;
      }
      if (h1) {
        r1 += (k4.x < d1 || (k4.x == d1 && j+0 < p1)) ? 1 : 0;
        r1 += (k4.y < d1 || (k4.y == d1 && j+1 < p1)) ? 1 : 0;
        r1 += (k4.z < d1 || (k4.z == d1 && j+2 < p1)) ? 1 : 0;
        r1 += (k4.w < d1 || (k4.w == d1 && j+3 < p1)) ? 1 : 0;
      }
    }
    if (h0) {
      *(float4*)&prm[r0*8]   = make_float4(psx[0], psy[0], pc00[0], pc11[0]);
      *(float4*)&prm[r0*8+4] = make_float4(pl2[0], pd[0],
                                 __int_as_float((w*128 + lane)*N_C), 0.0f);
    }
    if (h1) {
      *(float4*)&prm[r1*8]   = make_float4(psx[1], psy[1], pc00[1], pc11[1]);
      *(float4*)&prm[r1*8+4] = make_float4(pl2[1], pd[1],
                                 __int_as_float((w*128 + lane + 64)*N_C), 0.0f);
    }
  }
  __syncthreads();   // LAST barrier: prm complete; waves now fully independent

  // ---- main: barrier-free front-to-back walk (per wave) ----
  float T = 1.0f, dacc = 0.0f;
  float4 acc0 = {0,0,0,0}, acc1 = {0,0,0,0};   // groups g0 = cq+8w, g1 = g0+4
  const int g0 = cq + 8*w;
  const bool g1ok = (g0 + 4) < 30;
  const float* specg0 = spec + 4*g0;

  #pragma unroll 2
  for (int j = 0; j < nh; ++j) {
    float4 q0 = *(const float4*)&prm[j*8];       // uniform-addr ds_read_b128
    float4 q1 = *(const float4*)&prm[j*8+4];
    float dx = px - q0.x, dy = py - q0.y;
    float e = q1.x - (q0.z*dx*dx + q0.w*dy*dy);  // log2(alpha)
    if (__ballot(e > -30.0f)) {                  // alpha >= ~1e-9 anywhere?
      float a  = exp2f(e);
      float wv = a * T;
      T *= (1.0f - a);
      if (cq == 2) dacc = fmaf(q1.y, wv, dacc);
      const int sbase = __float_as_int(q1.z);    // src*120
      float4 s0 = *(const float4*)(specg0 + sbase);   // broadcast dwordx4
      acc0.x = fmaf(wv, s0.x, acc0.x);
      acc0.y = fmaf(wv, s0.y, acc0.y);
      acc0.z = fmaf(wv, s0.z, acc0.z);
      acc0.w = fmaf(wv, s0.w, acc0.w);
      if (g1ok) {
        float4 s1 = *(const float4*)(specg0 + sbase + 16);
        acc1.x = fmaf(wv, s1.x, acc1.x);
        acc1.y = fmaf(wv, s1.y, acc1.y);
        acc1.z = fmaf(wv, s1.z, acc1.z);
        acc1.w = fmaf(wv, s1.w, acc1.w);
      }
      if (!__ballot(T >= 1e-5f)) break;          // whole tile saturated
    }
  }

  // ---- epilogue: store wave-exclusive channel groups (no combine) ----
  if (inb) {
    const int pixi = y*IMG_W + x;
    const float bgT = T;                // BG*(1 - A_final), BG = 1.0
    float4 t0 = *(const float4*)&tm[4*g0];
    out[(4*g0+0)*HW + pixi] = (acc0.x + bgT)*t0.x;
    out[(4*g0+1)*HW + pixi] = (acc0.y + bgT)*t0.y;
    out[(4*g0+2)*HW + pixi] = (acc0.z + bgT)*t0.z;
    out[(4*g0+3)*HW + pixi] = (acc0.w + bgT)*t0.w;
    if (g1ok) {
      const int g1 = g0 + 4;
      float4 t1 = *(const float4*)&tm[4*g1];
      out[(4*g1+0)*HW + pixi] = (acc1.x + bgT)*t1.x;
      out[(4*g1+1)*HW + pixi] = (acc1.y + bgT)*t1.y;
      out[(4*g1+2)*HW + pixi] = (acc1.z + bgT)*t1.z;
      out[(4*g1+3)*HW + pixi] = (acc1.w + bgT)*t1.w;
    }
    if (cq == 2 && w == 0) out[N_C*HW + pixi] = dacc;          // depth
    if (cq == 3 && w == 0) out[N_C*HW + HW + pixi] = 1.0f - T; // A_final
  }
}

extern "C" void kernel_launch(void* const* d_in, const int* in_sizes, int n_in,
                              void* d_out, int out_size, void* d_ws, size_t ws_size,
                              hipStream_t stream) {
  const float* pos    = (const float*)d_in[0];
  // d_in[1] rotations: unused by the reference
  const float* scales = (const float*)d_in[2];
  const float* opac   = (const float*)d_in[3];
  const float* spec   = (const float*)d_in[4];
  const float* tm     = (const float*)d_in[5];
  const float* K      = (const float*)d_in[6];
  const float* E      = (const float*)d_in[7];
  float* out = (float*)d_out;
  (void)d_ws; (void)ws_size;   // no workspace needed

  k_render<<<NBLK, 256, 0, stream>>>(pos, scales, opac, K, E, spec, tm, out);
}